// Round 8
// baseline (223.740 us; speedup 1.0000x reference)
//
#include <hip/hip_runtime.h>

#define EPS 1e-5f

typedef __attribute__((ext_vector_type(8)))  short short8;
typedef __attribute__((ext_vector_type(4)))  short short4_t;
typedef __attribute__((ext_vector_type(16))) float f32x16;
typedef __attribute__((ext_vector_type(4)))  float f32x4;

__device__ inline unsigned f2bf(float f) {
    unsigned u = __builtin_bit_cast(unsigned, f);
    return (u + 0x7fffu + ((u >> 16) & 1u)) >> 16;   // RNE f32->bf16
}

// prep (unchanged from R7): two regions of d_ws
//  [0)      w2f:  bf16 w2 in mfma_f32_32x32x16_bf16 B-frag order
//           w2f[nf*8192 + ks*512 + lane*8 + e] = bf16(w2[ks*16+(lane>>5)*8+e][nf*32+(lane&31)])
//  [131072) embp: (emb + b2) as bf16 pairs, embp[row*128 + g*32 + c] =
//           pack(bf16(e[row][g*64+c]), bf16(e[row][g*64+32+c]))
__global__ void prep(const float* __restrict__ w2, const float* __restrict__ emb,
                     const float* __restrict__ b2,
                     unsigned short* __restrict__ w2f, unsigned* __restrict__ embp) {
    int idx = blockIdx.x * 256 + threadIdx.x;
    if (idx < 65536) {
        int e    = idx & 7;
        int lane = (idx >> 3) & 63;
        int ks   = (idx >> 9) & 15;
        int nf   = idx >> 13;
        int k    = ks * 16 + ((lane >> 5) << 3) + e;
        int n    = nf * 32 + (lane & 31);
        w2f[idx] = (unsigned short)f2bf(w2[k * 256 + n]);
    } else if (idx < 65536 + 12800) {
        int i   = idx - 65536;
        int row = i >> 7;
        int w   = i & 127;
        int g   = w >> 5;
        int c   = w & 31;
        int clo = g * 64 + c;
        int chi = clo + 32;
        unsigned lo = f2bf(emb[row * 256 + clo] + b2[clo]);
        unsigned hi = f2bf(emb[row * 256 + chi] + b2[chi]);
        embp[i] = lo | (hi << 16);
    }
}

// Cooperative 64-row tile per block; wave w owns output cols [64w, 64w+64)
// (nf = {2w, 2w+1}). Block reads w2f ONCE (each wave its disjoint slice),
// silu split by k-range, LayerNorm combined via LDS partials.
__global__ __launch_bounds__(256, 3) void fused_kernel(
    const int* __restrict__ z, const float* __restrict__ x,
    const float* __restrict__ w1, const float* __restrict__ b1,
    const unsigned short* __restrict__ w2f, const unsigned* __restrict__ embp,
    const float* __restrict__ gamma, const float* __restrict__ beta,
    float* __restrict__ out, int N)
{
    __shared__ char  a_lds[32768];        // [64][256] bf16, byte=row*512+col*2, ^((row&7)<<4)
    __shared__ float x_lds[64][4];
    __shared__ int   z_lds[64];
    __shared__ float part[64][4][2];      // [row][wave][sum,sq]

    const int tid  = threadIdx.x;
    const int wave = tid >> 6;
    const int lane = tid & 63;
    const int l31  = lane & 31;
    const int h    = lane >> 5;
    const int l15  = lane & 15;
    const int h4   = lane >> 4;

    const int R = blockIdx.x << 6;        // 64 rows per block

    if (tid < 64) {
        int r = R + tid;
        x_lds[tid][0] = x[r * 3 + 0];
        x_lds[tid][1] = x[r * 3 + 1];
        x_lds[tid][2] = x[r * 3 + 2];
        z_lds[tid]    = z[r];
    }
    __syncthreads();

    // ---- gather (emb+b2, packed bf16): 32 u32 loads/wave, into the accumulator
    // (C/D layout). Loads fly while the silu phase below executes.
    f32x16 acc[2][2];                     // [row-block][nf-half]
#pragma unroll
    for (int rb = 0; rb < 2; ++rb)
#pragma unroll
    for (int j = 0; j < 16; ++j) {
        const int row = rb * 32 + (j & 3) + ((j >> 2) << 3) + (h << 2);
        unsigned u = embp[z_lds[row] * 128 + wave * 32 + l31];
        acc[rb][0][j] = __builtin_bit_cast(float, u << 16);
        acc[rb][1][j] = __builtin_bit_cast(float, u & 0xffff0000u);
    }

    // per-lane epilogue constants (cols wave*64 + nfi*32 + l31)
    float gv[2], bv[2];
#pragma unroll
    for (int nfi = 0; nfi < 2; ++nfi) {
        int c = wave * 64 + nfi * 32 + l31;
        gv[nfi] = gamma[c]; bv[nfi] = beta[c];
    }

    // ---- silu: lane covers cols [c0, c0+4) of k-range; rows h4*16 + rr
    const int  c0  = wave * 64 + l15 * 4;
    const f32x4 w1a = *(const f32x4*)(w1 + c0);
    const f32x4 w1b = *(const f32x4*)(w1 + 256 + c0);
    const f32x4 w1c = *(const f32x4*)(w1 + 512 + c0);
    const f32x4 b1v = *(const f32x4*)(b1 + c0);
#pragma unroll
    for (int rr = 0; rr < 16; ++rr) {
        const int row = h4 * 16 + rr;
        float x0 = x_lds[row][0];
        float x1 = x_lds[row][1];
        float x2 = x_lds[row][2];
        short4_t pv;
#pragma unroll
        for (int j = 0; j < 4; ++j) {
            float tv = x0 * w1a[j] + x1 * w1b[j] + x2 * w1c[j] + b1v[j];
            float s  = tv * __builtin_amdgcn_rcpf(1.f + __expf(-tv));
            pv[j] = (short)f2bf(s);
        }
        int off = (row * 512 + c0 * 2) ^ ((row & 7) << 4);
        *(short4_t*)(a_lds + off) = pv;
    }
    __syncthreads();

    // ---- GEMM: [64,256] @ [256, 64-slice] via 4x mfma_f32_32x32x16_bf16 per ks.
    // Each wave streams only ITS 32KB slice of w2f -> block reads w2f once.
#pragma unroll
    for (int ks = 0; ks < 16; ++ks) {
        short8 a0 = *(const short8*)(a_lds + ((l31 * 512 + ks * 32 + h * 16) ^ ((l31 & 7) << 4)));
        short8 a1 = *(const short8*)(a_lds + (((32 + l31) * 512 + ks * 32 + h * 16) ^ ((l31 & 7) << 4)));
        const unsigned short* bp = w2f + ks * 512 + lane * 8;
        short8 b0 = *(const short8*)(bp + (2 * wave) * 8192);
        short8 b1f = *(const short8*)(bp + (2 * wave + 1) * 8192);
        acc[0][0] = __builtin_amdgcn_mfma_f32_32x32x16_bf16(a0, b0,  acc[0][0], 0, 0, 0);
        acc[0][1] = __builtin_amdgcn_mfma_f32_32x32x16_bf16(a0, b1f, acc[0][1], 0, 0, 0);
        acc[1][0] = __builtin_amdgcn_mfma_f32_32x32x16_bf16(a1, b0,  acc[1][0], 0, 0, 0);
        acc[1][1] = __builtin_amdgcn_mfma_f32_32x32x16_bf16(a1, b1f, acc[1][1], 0, 0, 0);
    }

    // ---- LN partials: per-wave sum/sq over its 64 cols, 5-step shfl in lane-half
#pragma unroll
    for (int rb = 0; rb < 2; ++rb)
#pragma unroll
    for (int j = 0; j < 16; ++j) {
        float s = acc[rb][0][j] + acc[rb][1][j];
        float q = acc[rb][0][j] * acc[rb][0][j] + acc[rb][1][j] * acc[rb][1][j];
#pragma unroll
        for (int d = 1; d < 32; d <<= 1) {
            s += __shfl_xor(s, d, 64);
            q += __shfl_xor(q, d, 64);
        }
        const int row = rb * 32 + (j & 3) + ((j >> 2) << 3) + (h << 2);
        if (l31 == 0) { part[row][wave][0] = s; part[row][wave][1] = q; }
    }
    __syncthreads();

    // ---- finalize: combine 4 partials per row, normalize, NT-store own slice
#pragma unroll
    for (int rb = 0; rb < 2; ++rb)
#pragma unroll
    for (int j = 0; j < 16; ++j) {
        const int row = rb * 32 + (j & 3) + ((j >> 2) << 3) + (h << 2);
        f32x4 p0 = *(const f32x4*)&part[row][0][0];
        f32x4 p1 = *(const f32x4*)&part[row][2][0];
        float sum = p0[0] + p0[2] + p1[0] + p1[2];
        float sq  = p0[1] + p0[3] + p1[1] + p1[3];
        float mu  = sum * (1.f / 256.f);
        float var = sq * (1.f / 256.f) - mu * mu;
        float rs  = rsqrtf(var + EPS);
        float* orow = out + (size_t)(R + row) * 256 + wave * 64 + l31;
#pragma unroll
        for (int nfi = 0; nfi < 2; ++nfi)
            __builtin_nontemporal_store((acc[rb][nfi][j] - mu) * rs * gv[nfi] + bv[nfi],
                                        orow + nfi * 32);
    }
}

extern "C" void kernel_launch(void* const* d_in, const int* in_sizes, int n_in,
                              void* d_out, int out_size, void* d_ws, size_t ws_size,
                              hipStream_t stream) {
    const int*   z     = (const int*)d_in[0];
    const float* x     = (const float*)d_in[1];
    const float* emb   = (const float*)d_in[2];
    const float* w1    = (const float*)d_in[3];
    const float* b1    = (const float*)d_in[4];
    const float* w2    = (const float*)d_in[5];
    const float* b2    = (const float*)d_in[6];
    const float* gamma = (const float*)d_in[7];
    const float* beta  = (const float*)d_in[8];
    float* out = (float*)d_out;
    const int N = in_sizes[0];

    unsigned short* w2f  = (unsigned short*)d_ws;              // 128 KB
    unsigned*       embp = (unsigned*)((char*)d_ws + 131072);  // 50 KB bf16-pair emb+b2

    prep<<<(65536 + 12800 + 255) / 256, 256, 0, stream>>>(w2, emb, b2, w2f, embp);

    int blocks = N >> 6;                  // one 64-row tile per block, one-shot
    fused_kernel<<<blocks, 256, 0, stream>>>(z, x, w1, b1, w2f, embp,
                                             gamma, beta, out, N);
}

// Round 9
// 189.015 us; speedup vs baseline: 1.1837x; 1.1837x over previous
//
#include <hip/hip_runtime.h>

#define EPS 1e-5f
#define WAVES 4

typedef __attribute__((ext_vector_type(8)))  short short8;
typedef __attribute__((ext_vector_type(4)))  short short4_t;
typedef __attribute__((ext_vector_type(16))) float f32x16;
typedef __attribute__((ext_vector_type(4)))  float f32x4;

__device__ inline unsigned f2bf(float f) {
    unsigned u = __builtin_bit_cast(unsigned, f);
    return (u + 0x7fffu + ((u >> 16) & 1u)) >> 16;   // RNE f32->bf16
}

// prep (unchanged from R7): two regions of d_ws
//  [0)      w2f:  bf16 w2 in mfma_f32_32x32x16_bf16 B-frag order
//  [131072) embp: (emb + b2) as bf16 pairs
__global__ void prep(const float* __restrict__ w2, const float* __restrict__ emb,
                     const float* __restrict__ b2,
                     unsigned short* __restrict__ w2f, unsigned* __restrict__ embp) {
    int idx = blockIdx.x * 256 + threadIdx.x;
    if (idx < 65536) {
        int e    = idx & 7;
        int lane = (idx >> 3) & 63;
        int ks   = (idx >> 9) & 15;
        int nf   = idx >> 13;
        int k    = ks * 16 + ((lane >> 5) << 3) + e;
        int n    = nf * 32 + (lane & 31);
        w2f[idx] = (unsigned short)f2bf(w2[k * 256 + n]);
    } else if (idx < 65536 + 12800) {
        int i   = idx - 65536;
        int row = i >> 7;
        int w   = i & 127;
        int g   = w >> 5;
        int c   = w & 31;
        int clo = g * 64 + c;
        int chi = clo + 32;
        unsigned lo = f2bf(emb[row * 256 + clo] + b2[clo]);
        unsigned hi = f2bf(emb[row * 256 + chi] + b2[chi]);
        embp[i] = lo | (hi << 16);
    }
}

__global__ __launch_bounds__(256, 2) void fused_kernel(
    const int* __restrict__ z, const float* __restrict__ x,
    const float* __restrict__ w1, const float* __restrict__ b1,
    const unsigned short* __restrict__ w2f, const unsigned* __restrict__ embp,
    const float* __restrict__ gamma, const float* __restrict__ beta,
    float* __restrict__ out, int N)
{
    // All LDS PER-WAVE: no __syncthreads (within-wave producer/consumer; DS pipe
    // is in-order per wave). One-shot 32-row tile per wave (R7 structure).
    __shared__ char  p_lds[WAVES * 16384];   // per-wave: A-tile, then store-stage
    __shared__ float x_lds[WAVES][32][4];
    __shared__ int   z_lds[WAVES][32];

    const int tid  = threadIdx.x;
    const int wave = tid >> 6;
    const int lane = tid & 63;
    const int l31  = lane & 31;
    const int h    = lane >> 5;
    char* pbuf = p_lds + wave * 16384;

    const int tiles = N >> 5;
    const int t = blockIdx.x * WAVES + wave;
    if (t >= tiles) return;                  // per-wave exit legal: no barriers
    const int R = t << 5;

    if (lane < 32) {
        int r = R + lane;
        x_lds[wave][lane][0] = x[r * 3 + 0];
        x_lds[wave][lane][1] = x[r * 3 + 1];
        x_lds[wave][lane][2] = x[r * 3 + 2];
        z_lds[wave][lane]    = z[r];
    }

    // ---- init acc with packed-bf16 (emb+b2) gather (C/D layout): 64 u32 loads
    // fly while the silu chain below executes.
    f32x16 acc[8];
#pragma unroll
    for (int j = 0; j < 16; ++j) {
        const int rl = (j & 3) + ((j >> 2) << 3) + (h << 2);
        const unsigned* er = embp + z_lds[wave][rl] * 128 + l31;
#pragma unroll
        for (int g = 0; g < 4; ++g) {
            unsigned u = er[g * 32];
            acc[2 * g][j]     = __builtin_bit_cast(float, u << 16);
            acc[2 * g + 1][j] = __builtin_bit_cast(float, u & 0xffff0000u);
        }
    }

    // hoisted per-lane weights: this lane computes p columns [lane*4, lane*4+3]
    const int  c0  = lane * 4;
    const f32x4 w1a = *(const f32x4*)(w1 + c0);
    const f32x4 w1b = *(const f32x4*)(w1 + 256 + c0);
    const f32x4 w1c = *(const f32x4*)(w1 + 512 + c0);
    const f32x4 b1v = *(const f32x4*)(b1 + c0);
    float gv[8], bv[8];
#pragma unroll
    for (int nf = 0; nf < 8; ++nf) {
        int c = nf * 32 + l31;
        gv[nf] = gamma[c]; bv[nf] = beta[c];
    }

    // p = silu(x @ w1 + b1) -> bf16 LDS tile, XOR-swizzled rows
#pragma unroll
    for (int r = 0; r < 32; ++r) {
        float x0 = x_lds[wave][r][0];
        float x1 = x_lds[wave][r][1];
        float x2 = x_lds[wave][r][2];
        short4_t pv;
#pragma unroll
        for (int j = 0; j < 4; ++j) {
            float tv = x0 * w1a[j] + x1 * w1b[j] + x2 * w1c[j] + b1v[j];
            float s  = tv * __builtin_amdgcn_rcpf(1.f + __expf(-tv));
            pv[j] = (short)f2bf(s);
        }
        int off = (r * 512 + lane * 8) ^ ((r & 7) << 4);
        *(short4_t*)(pbuf + off) = pv;
    }

    // GEMM: [32,256] @ [256,256] via mfma_f32_32x32x16_bf16 (acc has emb+b2)
#pragma unroll
    for (int ks = 0; ks < 16; ++ks) {
        int aoff = (l31 * 512 + ks * 32 + h * 16) ^ ((l31 & 7) << 4);
        short8 a = *(const short8*)(pbuf + aoff);
        const unsigned short* bp = w2f + ks * 512 + lane * 8;
#pragma unroll
        for (int nf = 0; nf < 8; ++nf) {
            short8 b = *(const short8*)(bp + nf * 8192);
            acc[nf] = __builtin_amdgcn_mfma_f32_32x32x16_bf16(a, b, acc[nf], 0, 0, 0);
        }
    }

    // ---- epilogue: LayerNorm, stage 16 normalized rows in the dead A-tile,
    // then flush each row as ONE 1KB-contiguous NT store (64 lanes x 16B).
    // NT avoids L2 write-allocate RFO; 1KB contiguity avoids the ~2x
    // write-through amplification seen with 128B-interleaved NT stores (R5 ctr).
    float* pf = (float*)pbuf;                // reuse per-wave 16KB as [16][256] f32
#pragma unroll
    for (int half = 0; half < 2; ++half) {
#pragma unroll
        for (int jj = 0; jj < 8; ++jj) {
            const int j  = half * 8 + jj;
            const int rl = (j & 3) + ((j >> 2) << 3) + (h << 2);   // row within 32
            float hv[8];
            float hsum = 0.f, hsq = 0.f;
#pragma unroll
            for (int nf = 0; nf < 8; ++nf) {
                float v = acc[nf][j];
                hv[nf] = v; hsum += v; hsq += v * v;
            }
#pragma unroll
            for (int d = 1; d < 32; d <<= 1) {    // row lives in one lane-half
                hsum += __shfl_xor(hsum, d, 64);
                hsq  += __shfl_xor(hsq,  d, 64);
            }
            float mu  = hsum * (1.f / 256.f);
            float var = hsq * (1.f / 256.f) - mu * mu;
            float rs  = rsqrtf(var + EPS);
            float* prow = pf + (rl & 15) * 256 + l31;   // 2 lanes/bank: free
#pragma unroll
            for (int nf = 0; nf < 8; ++nf)
                prow[nf * 32] = (hv[nf] - mu) * rs * gv[nf] + bv[nf];
        }
        // flush 16 rows: one full 1KB row per NT store instruction
#pragma unroll
        for (int rr = 0; rr < 16; ++rr) {
            f32x4 v = *(const f32x4*)(pf + rr * 256 + lane * 4);
            __builtin_nontemporal_store(
                v, (f32x4*)(out + (size_t)(R + half * 16 + rr) * 256 + lane * 4));
        }
    }
}

extern "C" void kernel_launch(void* const* d_in, const int* in_sizes, int n_in,
                              void* d_out, int out_size, void* d_ws, size_t ws_size,
                              hipStream_t stream) {
    const int*   z     = (const int*)d_in[0];
    const float* x     = (const float*)d_in[1];
    const float* emb   = (const float*)d_in[2];
    const float* w1    = (const float*)d_in[3];
    const float* b1    = (const float*)d_in[4];
    const float* w2    = (const float*)d_in[5];
    const float* b2    = (const float*)d_in[6];
    const float* gamma = (const float*)d_in[7];
    const float* beta  = (const float*)d_in[8];
    float* out = (float*)d_out;
    const int N = in_sizes[0];

    unsigned short* w2f  = (unsigned short*)d_ws;              // 128 KB
    unsigned*       embp = (unsigned*)((char*)d_ws + 131072);  // 50 KB bf16-pair emb+b2

    prep<<<(65536 + 12800 + 255) / 256, 256, 0, stream>>>(w2, emb, b2, w2f, embp);

    int tiles  = N >> 5;
    int blocks = (tiles + WAVES - 1) / WAVES;  // one tile per wave, one-shot
    fused_kernel<<<blocks, 256, 0, stream>>>(z, x, w1, b1, w2f, embp,
                                             gamma, beta, out, N);
}